// Round 14
// baseline (355.661 us; speedup 1.0000x reference)
//
#include <hip/hip_runtime.h>
#include <stdint.h>

typedef float f32x4 __attribute__((ext_vector_type(4)));
typedef short s16x8 __attribute__((ext_vector_type(8)));
typedef unsigned short u16x4 __attribute__((ext_vector_type(4)));
typedef unsigned short u16x8 __attribute__((ext_vector_type(8)));

#define SCALE_F 0.08838834764831845f

__device__ __forceinline__ unsigned short f32_to_bf16(float f) {
    union { float f; unsigned int u; } v; v.f = f;
    return (unsigned short)((v.u + 0x7FFFu + ((v.u >> 16) & 1u)) >> 16);
}
__device__ __forceinline__ float bf16_to_f32(unsigned short h) {
    union { unsigned int u; float f; } v; v.u = (unsigned int)h << 16;
    return v.f;
}

__device__ __forceinline__ void gload16(const void* g, void* l) {
    __builtin_amdgcn_global_load_lds((const __attribute__((address_space(1))) unsigned int*)g,
                                     (__attribute__((address_space(3))) unsigned int*)l,
                                     16, 0, 0);
}

// ---------------- fp32 -> bf16 elementwise ----------------
__global__ void k_conv_bf16(const float* __restrict__ in, unsigned short* __restrict__ out, int n4) {
    int i = blockIdx.x * 256 + threadIdx.x;
    if (i >= n4) return;
    f32x4 v = ((const f32x4*)in)[i];
    u16x4 o;
    o[0] = f32_to_bf16(v[0]); o[1] = f32_to_bf16(v[1]);
    o[2] = f32_to_bf16(v[2]); o[3] = f32_to_bf16(v[3]);
    ((u16x4*)out)[i] = o;
}

// ------- fp32 [R][in_ld] (col offset in_off) -> bf16 [C][R] -------
__global__ void k_transpose_f32(const float* __restrict__ in, unsigned short* __restrict__ out,
                                int R, int in_ld, int in_off) {
    __shared__ float tile[64][65];
    const int rb = blockIdx.y * 64, cb = blockIdx.x * 64;
    const int t = threadIdx.x;
    const int lr = t >> 4, lc4 = (t & 15) * 4;
#pragma unroll
    for (int i = 0; i < 4; ++i) {
        int r = i * 16 + lr;
        f32x4 v = *(const f32x4*)(in + (size_t)(rb + r) * in_ld + in_off + cb + lc4);
        tile[r][lc4 + 0] = v[0]; tile[r][lc4 + 1] = v[1];
        tile[r][lc4 + 2] = v[2]; tile[r][lc4 + 3] = v[3];
    }
    __syncthreads();
#pragma unroll
    for (int i = 0; i < 4; ++i) {
        int oc = cb + i * 16 + lr;
        u16x4 o;
#pragma unroll
        for (int j = 0; j < 4; ++j)
            o[j] = f32_to_bf16(tile[lc4 + j][i * 16 + lr]);
        *(u16x4*)(out + (size_t)oc * R + rb + lc4) = o;
    }
}

// ------- bf16 [R][in_ld] (col offset in_off) -> bf16 [C][R] -------
__global__ void k_transpose_b16(const unsigned short* __restrict__ in, unsigned short* __restrict__ out,
                                int R, int in_ld, int in_off) {
    __shared__ unsigned short tile[64][68];
    const int rb = blockIdx.y * 64, cb = blockIdx.x * 64;
    const int t = threadIdx.x;
    const int lr = t >> 4, lc4 = (t & 15) * 4;
#pragma unroll
    for (int i = 0; i < 4; ++i) {
        int r = i * 16 + lr;
        u16x4 v = *(const u16x4*)(in + (size_t)(rb + r) * in_ld + in_off + cb + lc4);
        tile[r][lc4 + 0] = v[0]; tile[r][lc4 + 1] = v[1];
        tile[r][lc4 + 2] = v[2]; tile[r][lc4 + 3] = v[3];
    }
    __syncthreads();
#pragma unroll
    for (int i = 0; i < 4; ++i) {
        int oc = cb + i * 16 + lr;
        u16x4 o;
#pragma unroll
        for (int j = 0; j < 4; ++j)
            o[j] = tile[lc4 + j][i * 16 + lr];
        *(u16x4*)(out + (size_t)oc * R + rb + lc4) = o;
    }
}

// ======== gemmA: BM=128, BN=384, BK=64, full-fill grid 16x16=256, bn-major swizzle ========
__global__ __launch_bounds__(512, 1)
void k_gemmA(const unsigned short* __restrict__ A, const unsigned short* __restrict__ Bt,
             unsigned short* __restrict__ C, int N, int K) {
    __shared__ __align__(16) unsigned short As[2][2][4096];
    __shared__ __align__(16) unsigned short Bs[2][2][12288];
    const int tid = threadIdx.x;
    const int lane = tid & 63, wid = tid >> 6;
    const int g = lane >> 4, l15 = lane & 15;
    const int wm = wid >> 2, wn = wid & 3;
    const int nwg = gridDim.x, bid = blockIdx.x;
    const int swz = (bid & 7) * (nwg >> 3) + (bid >> 3);   // bijective: 256 % 8 == 0
    const int bn = swz >> 4, bm = swz & 15;                // bn-major XCD ownership
    const int brow = bm << 7, bcol = bn * 384;

    const int rS = tid >> 2;
    const int kcS = (tid & 3) ^ (rS & 3) ^ ((rS >> 2) & 3);
    const unsigned short* sA = A + (size_t)(brow + rS) * K + kcS * 8;
    const unsigned short* sB = Bt + (size_t)(bcol + rS) * K + kcS * 8;
    const int fsw = (g ^ (l15 & 3) ^ ((l15 >> 2) & 3)) * 8;

    f32x4 acc[4][6] = {};
    const int nt = K >> 6;

    auto stA = [&](int t, int kh) {
        gload16(sA + (size_t)t * 64 + kh * 32, &As[t & 1][kh][tid * 8]);
    };
    auto stB = [&](int t, int kh) {
        unsigned short* d = &Bs[t & 1][kh][tid * 8];
        const unsigned short* s = sB + (size_t)t * 64 + kh * 32;
        gload16(s, d);
        gload16(s + (size_t)128 * K, d + 4096);
        gload16(s + (size_t)256 * K, d + 8192);
    };

    stA(0, 0); stB(0, 0); stA(0, 1); stB(0, 1);

    for (int t = 0; t < nt; ++t) {
        const int c = t & 1;
#pragma unroll
        for (int kh = 0; kh < 2; ++kh) {
            if (t + 1 < nt)   { stA(t + 1, kh); stB(t + 1, kh); asm volatile("s_waitcnt vmcnt(8)" ::: "memory"); }
            else if (kh == 0) { asm volatile("s_waitcnt vmcnt(4)" ::: "memory"); }
            else              { asm volatile("s_waitcnt vmcnt(0)" ::: "memory"); }
            __builtin_amdgcn_s_barrier();
            s16x8 af[4], bf[6];
#pragma unroll
            for (int f = 0; f < 4; ++f)
                af[f] = *(const s16x8*)(&As[c][kh][(wm * 64 + f * 16 + l15) * 32 + fsw]);
#pragma unroll
            for (int j = 0; j < 6; ++j)
                bf[j] = *(const s16x8*)(&Bs[c][kh][(wn * 96 + j * 16 + l15) * 32 + fsw]);
            __builtin_amdgcn_s_setprio(1);
#pragma unroll
            for (int f = 0; f < 4; ++f)
#pragma unroll
                for (int j = 0; j < 6; ++j)
                    acc[f][j] = __builtin_amdgcn_mfma_f32_16x16x32_bf16(af[f], bf[j], acc[f][j], 0, 0, 0);
            __builtin_amdgcn_s_setprio(0);
        }
    }

#pragma unroll
    for (int f = 0; f < 4; ++f)
#pragma unroll
        for (int j = 0; j < 6; ++j)
#pragma unroll
            for (int r = 0; r < 4; ++r)
                C[(size_t)(brow + wm * 64 + f * 16 + g * 4 + r) * N
                  + bcol + wn * 96 + j * 16 + l15] = f32_to_bf16(acc[f][j][r]);
}

// ======== gemmB: BM=128, BN=256, BK=64, 2 phases/tile, bn-major swizzle ========
__global__ __launch_bounds__(512, 1)
void k_gemmB(const unsigned short* __restrict__ A, const unsigned short* __restrict__ Bt,
             float* __restrict__ C, int N, int K) {
    __shared__ __align__(16) unsigned short As[2][2][4096];
    __shared__ __align__(16) unsigned short Bs[2][2][8192];
    const int tid = threadIdx.x;
    const int lane = tid & 63, wid = tid >> 6;
    const int g = lane >> 4, l15 = lane & 15;
    const int wm = wid >> 2, wn = wid & 3;
    const int nwg = gridDim.x, bid = blockIdx.x;
    const int swz = (bid & 7) * (nwg >> 3) + (bid >> 3);
    const int bn = swz >> 4, bm = swz & 15;
    const int brow = bm << 7, bcol = bn << 8;

    const int rS = tid >> 2;
    const int kcS = (tid & 3) ^ (rS & 3) ^ ((rS >> 2) & 3);
    const unsigned short* sA = A + (size_t)(brow + rS) * K + kcS * 8;
    const unsigned short* sB = Bt + (size_t)(bcol + rS) * K + kcS * 8;
    const int fsw = (g ^ (l15 & 3) ^ ((l15 >> 2) & 3)) * 8;

    f32x4 acc[4][4] = {};
    const int nt = K >> 6;

    auto stA = [&](int t, int kh) {
        gload16(sA + (size_t)t * 64 + kh * 32, &As[t & 1][kh][tid * 8]);
    };
    auto stB = [&](int t, int kh) {
        unsigned short* d = &Bs[t & 1][kh][tid * 8];
        const unsigned short* s = sB + (size_t)t * 64 + kh * 32;
        gload16(s, d);
        gload16(s + (size_t)128 * K, d + 4096);
    };

    stA(0, 0); stB(0, 0); stA(0, 1); stB(0, 1);

    for (int t = 0; t < nt; ++t) {
        const int c = t & 1;
#pragma unroll
        for (int kh = 0; kh < 2; ++kh) {
            if (t + 1 < nt) { stA(t + 1, kh); stB(t + 1, kh); asm volatile("s_waitcnt vmcnt(6)" ::: "memory"); }
            else if (kh == 0) { asm volatile("s_waitcnt vmcnt(3)" ::: "memory"); }
            else              { asm volatile("s_waitcnt vmcnt(0)" ::: "memory"); }
            __builtin_amdgcn_s_barrier();
            s16x8 af[4], bf[4];
#pragma unroll
            for (int f = 0; f < 4; ++f)
                af[f] = *(const s16x8*)(&As[c][kh][(wm * 64 + f * 16 + l15) * 32 + fsw]);
#pragma unroll
            for (int j = 0; j < 4; ++j)
                bf[j] = *(const s16x8*)(&Bs[c][kh][(wn * 64 + j * 16 + l15) * 32 + fsw]);
            __builtin_amdgcn_s_setprio(1);
#pragma unroll
            for (int f = 0; f < 4; ++f)
#pragma unroll
                for (int j = 0; j < 4; ++j)
                    acc[f][j] = __builtin_amdgcn_mfma_f32_16x16x32_bf16(af[f], bf[j], acc[f][j], 0, 0, 0);
            __builtin_amdgcn_s_setprio(0);
        }
    }

#pragma unroll
    for (int f = 0; f < 4; ++f)
#pragma unroll
        for (int j = 0; j < 4; ++j)
#pragma unroll
            for (int r = 0; r < 4; ++r)
                C[(size_t)(brow + wm * 64 + f * 16 + g * 4 + r) * N
                  + bcol + wn * 64 + j * 16 + l15] = acc[f][j][r];
}

// ---------------- vectorized RoPE + pack Q/K; Q pre-scaled by 1/sqrt(D) ----------------
__global__ void k_rope_pack(const unsigned short* __restrict__ qkv, const float* __restrict__ cosT,
                            const float* __restrict__ sinT, unsigned short* __restrict__ Qb,
                            unsigned short* __restrict__ Kb) {
    const int oct = blockIdx.x * 128 + threadIdx.x;
    if (oct >= 640) return;
    const int col = oct * 8;
    const int t = blockIdx.y;
    const int d = col & 127;
    const bool isQ = (col < 4096);
    const float post = isQ ? SCALE_F : 1.0f;
    u16x8 v8 = *(const u16x8*)(qkv + (size_t)t * 6144 + col);
    u16x8 o8;
    if (d < 64) {
        u16x8 p8 = *(const u16x8*)(qkv + (size_t)t * 6144 + (col ^ 32));
        f32x4 c0 = *(const f32x4*)(cosT + t * 64 + d);
        f32x4 c1 = *(const f32x4*)(cosT + t * 64 + d + 4);
        f32x4 s0 = *(const f32x4*)(sinT + t * 64 + d);
        f32x4 s1 = *(const f32x4*)(sinT + t * 64 + d + 4);
        const float sgn = (d < 32) ? -1.f : 1.f;
#pragma unroll
        for (int j = 0; j < 8; ++j) {
            float cc = (j < 4) ? c0[j] : c1[j - 4];
            float ss = (j < 4) ? s0[j] : s1[j - 4];
            float o = (bf16_to_f32(v8[j]) * cc + sgn * bf16_to_f32(p8[j]) * ss) * post;
            o8[j] = f32_to_bf16(o);
        }
    } else {
#pragma unroll
        for (int j = 0; j < 8; ++j)
            o8[j] = f32_to_bf16(bf16_to_f32(v8[j]) * post);
    }
    if (isQ) {
        const int h = col >> 7;
        *(u16x8*)(Qb + ((size_t)h * 2048 + t) * 128 + d) = o8;
    } else {
        const int hk = (col - 4096) >> 7;
        *(u16x8*)(Kb + ((size_t)hk * 2048 + t) * 128 + d) = o8;
    }
}

// ------- causal GQA flash attention: 512-thr blocks, TWO q-tile pairs per block -------
// Block bid owns tiles {bid, 31-bid, bid+8, 23-bid}. Wave w<4: (tile bid, slice w)
// + (tile 31-bid, slice w); w>=4: (bid+8, w-4) + (23-bid, w-4). Per-wave work = 33
// tile-processes for EVERY wave (uniform). Barriers/stages per compute halved;
// K/V traffic -42%. Grid (8,32)=256 blocks = 1/CU. LDS 96KB.
__global__ __launch_bounds__(512, 1)
void k_attn(const unsigned short* __restrict__ Qb, const unsigned short* __restrict__ Kb,
            const unsigned short* __restrict__ Vt, unsigned short* __restrict__ Ob) {
    __shared__ __align__(16) unsigned short Ks[2][8192];   // [chunk16][key64][8]
    __shared__ __align__(16) unsigned short Vs[2][8192];   // [kc8][d128][8]
    __shared__ __align__(16) unsigned short Pl[8][2][1024];
    const int h = blockIdx.y, hk = h >> 2;
    const int bid = blockIdx.x;                 // 0..7
    const int tid = threadIdx.x, lane = tid & 63, wid = tid >> 6;
    const int g = lane >> 4, l15 = lane & 15;
    const int sl = (wid & 3) * 16;
    const int qb0 = (wid < 4) ? bid : bid + 8;          // light tile
    const int qb1 = (wid < 4) ? 31 - bid : 23 - bid;    // heavy tile (qb1 > qb0)
    const int qr0 = qb0 * 64 + sl, qr1 = qb1 * 64 + sl;
    const int swz = (l15 & 7) << 4;

    s16x8 aq0[4], aq1[4];
#pragma unroll
    for (int kc = 0; kc < 4; ++kc) {
        aq0[kc] = *(const s16x8*)(Qb + ((size_t)h * 2048 + qr0 + l15) * 128 + kc * 32 + g * 8);
        aq1[kc] = *(const s16x8*)(Qb + ((size_t)h * 2048 + qr1 + l15) * 128 + kc * 32 + g * 8);
    }

    // staging (512 threads): K chunk = tid>>6 (+8 per i), V chunk = tid>>7 (+4 per i)
    const unsigned short* gK = Kb + ((size_t)hk * 2048 + (tid & 63)) * 128 + (tid >> 6) * 8;
    const unsigned short* gV = Vt + ((size_t)hk * 128 + (tid & 127)) * 2048 + (tid >> 7) * 8;

    auto stage = [&](int kb) {
        unsigned short* dK = Ks[kb & 1] + tid * 8;
        unsigned short* dV = Vs[kb & 1] + tid * 8;
        const unsigned short* sK = gK + (size_t)kb * 8192;
        const unsigned short* sV = gV + kb * 64;
#pragma unroll
        for (int i = 0; i < 2; ++i) gload16(sK + i * 64, dK + i * 4096);
#pragma unroll
        for (int i = 0; i < 2; ++i) gload16(sV + i * 32, dV + i * 4096);
    };

    f32x4 oacc0[8] = {}, oacc1[8] = {};
    float m0 = -1e30f, l0 = 0.f, m1 = -1e30f, l1 = 0.f;

    auto sm = [&](f32x4* s, f32x4* oacc, float& mr, float& lr, int qrow0, int kb, char* pw) {
        const int q = qrow0 + l15;
        if (kb * 64 + 63 > qrow0) {
#pragma unroll
            for (int kt = 0; kt < 4; ++kt)
#pragma unroll
                for (int r = 0; r < 4; ++r)
                    if (kb * 64 + kt * 16 + g * 4 + r > q) s[kt][r] = -3e38f;
        }
        float mx = -3e38f;
#pragma unroll
        for (int kt = 0; kt < 4; ++kt)
#pragma unroll
            for (int r = 0; r < 4; ++r) mx = fmaxf(mx, s[kt][r]);
        mx = fmaxf(mx, __shfl_xor(mx, 16));
        mx = fmaxf(mx, __shfl_xor(mx, 32));
        if (!__all(mx - mr <= 8.0f)) {        // T13 defer-max
            const float mnew = fmaxf(mr, mx);
            const float scal = __expf(mr - mnew);
            mr = mnew;
            float so[4];
#pragma unroll
            for (int r = 0; r < 4; ++r) so[r] = __shfl(scal, g * 4 + r, 16);
#pragma unroll
            for (int j = 0; j < 8; ++j) {
                oacc[j][0] *= so[0]; oacc[j][1] *= so[1];
                oacc[j][2] *= so[2]; oacc[j][3] *= so[3];
            }
            lr *= scal;
        }
        float ps = 0.f;
#pragma unroll
        for (int kt = 0; kt < 4; ++kt)
#pragma unroll
            for (int r = 0; r < 4; ++r) {
                float p = __expf(s[kt][r] - mr);
                s[kt][r] = p;
                ps += p;
            }
        ps += __shfl_xor(ps, 16);
        ps += __shfl_xor(ps, 32);
        lr += ps;
#pragma unroll
        for (int kt = 0; kt < 4; ++kt) {
            unsigned int w0 = (unsigned int)f32_to_bf16(s[kt][0]) | ((unsigned int)f32_to_bf16(s[kt][1]) << 16);
            unsigned int w1 = (unsigned int)f32_to_bf16(s[kt][2]) | ((unsigned int)f32_to_bf16(s[kt][3]) << 16);
            const int b0 = (l15 * 128 + kt * 32 + g * 8) ^ swz;
            *(unsigned int*)(pw + b0) = w0;
            *(unsigned int*)(pw + b0 + 4) = w1;
        }
    };

    const int nkb = 32 - bid;        // covers qb1 max = 31-bid
    stage(0);
    for (int kb = 0; kb < nkb; ++kb) {
        if (kb + 1 < nkb) {
            stage(kb + 1);
            asm volatile("s_waitcnt vmcnt(4)" ::: "memory");
        } else {
            asm volatile("s_waitcnt vmcnt(0)" ::: "memory");
        }
        __builtin_amdgcn_s_barrier();
        const unsigned short* ks = Ks[kb & 1];
        const unsigned short* vs = Vs[kb & 1];
        char* pw0 = (char*)Pl[wid][0];
        char* pw1 = (char*)Pl[wid][1];
        const bool a0 = (kb <= qb0);         // a0 implies a1
        const bool a1 = (kb <= qb1);
        f32x4 s0_[4] = {}, s1_[4] = {};
        if (a1) {
            __builtin_amdgcn_s_setprio(1);
            if (a0) {
#pragma unroll
                for (int kc = 0; kc < 4; ++kc)
#pragma unroll
                    for (int kt = 0; kt < 4; ++kt) {
                        s16x8 kf = *(const s16x8*)(ks + ((kc * 4 + g) * 64 + kt * 16 + l15) * 8);
                        s1_[kt] = __builtin_amdgcn_mfma_f32_16x16x32_bf16(kf, aq1[kc], s1_[kt], 0, 0, 0);
                        s0_[kt] = __builtin_amdgcn_mfma_f32_16x16x32_bf16(kf, aq0[kc], s0_[kt], 0, 0, 0);
                    }
            } else {
#pragma unroll
                for (int kc = 0; kc < 4; ++kc)
#pragma unroll
                    for (int kt = 0; kt < 4; ++kt) {
                        s16x8 kf = *(const s16x8*)(ks + ((kc * 4 + g) * 64 + kt * 16 + l15) * 8);
                        s1_[kt] = __builtin_amdgcn_mfma_f32_16x16x32_bf16(kf, aq1[kc], s1_[kt], 0, 0, 0);
                    }
            }
            __builtin_amdgcn_s_setprio(0);
            sm(s1_, oacc1, m1, l1, qr1, kb, pw1);
            if (a0) sm(s0_, oacc0, m0, l0, qr0, kb, pw0);
            __builtin_amdgcn_s_setprio(1);
            if (a0) {
#pragma unroll
                for (int kc = 0; kc < 2; ++kc) {
                    s16x8 pa1 = *(const s16x8*)(pw1 + ((l15 * 128 + kc * 64 + g * 16) ^ swz));
                    s16x8 pa0 = *(const s16x8*)(pw0 + ((l15 * 128 + kc * 64 + g * 16) ^ swz));
#pragma unroll
                    for (int j = 0; j < 8; ++j) {
                        s16x8 bv = *(const s16x8*)(vs + ((kc * 4 + g) * 128 + j * 16 + l15) * 8);
                        oacc1[j] = __builtin_amdgcn_mfma_f32_16x16x32_bf16(pa1, bv, oacc1[j], 0, 0, 0);
                        oacc0[j] = __builtin_amdgcn_mfma_f32_16x16x32_bf16(pa0, bv, oacc0[j], 0, 0, 0);
                    }
                }
            } else {
#pragma unroll
                for (int kc = 0; kc < 2; ++kc) {
                    s16x8 pa1 = *(const s16x8*)(pw1 + ((l15 * 128 + kc * 64 + g * 16) ^ swz));
#pragma unroll
                    for (int j = 0; j < 8; ++j) {
                        s16x8 bv = *(const s16x8*)(vs + ((kc * 4 + g) * 128 + j * 16 + l15) * 8);
                        oacc1[j] = __builtin_amdgcn_mfma_f32_16x16x32_bf16(pa1, bv, oacc1[j], 0, 0, 0);
                    }
                }
            }
            __builtin_amdgcn_s_setprio(0);
        }
        __builtin_amdgcn_s_barrier();
    }
    float li0[4], li1[4];
#pragma unroll
    for (int r = 0; r < 4; ++r) {
        li0[r] = 1.f / __shfl(l0, g * 4 + r, 16);
        li1[r] = 1.f / __shfl(l1, g * 4 + r, 16);
    }
#pragma unroll
    for (int j = 0; j < 8; ++j)
#pragma unroll
        for (int r = 0; r < 4; ++r) {
            Ob[(size_t)(qr0 + g * 4 + r) * 4096 + h * 128 + j * 16 + l15] = f32_to_bf16(oacc0[j][r] * li0[r]);
            Ob[(size_t)(qr1 + g * 4 + r) * 4096 + h * 128 + j * 16 + l15] = f32_to_bf16(oacc1[j][r] * li1[r]);
        }
}

extern "C" void kernel_launch(void* const* d_in, const int* in_sizes, int n_in,
                              void* d_out, int out_size, void* d_ws, size_t ws_size,
                              hipStream_t stream) {
    const float* x     = (const float*)d_in[0];
    const float* cosT  = (const float*)d_in[2];
    const float* sinT  = (const float*)d_in[3];
    const float* w_qkv = (const float*)d_in[4];
    const float* w_o   = (const float*)d_in[5];
    float* out = (float*)d_out;

    char* ws = (char*)d_ws;
    unsigned short* wT   = (unsigned short*)(ws + 0);           // 50.3 MB (w_qkv^T / w_o^T)
    unsigned short* qkvb = (unsigned short*)(ws + 50331648);    // 25.2 MB bf16 qkv
    unsigned short* Ob   = (unsigned short*)(ws + 50331648);    // reuse after rope+t_V
    unsigned short* xb   = (unsigned short*)(ws + 100663296);   // 16.8 MB
    unsigned short* Qb   = xb;                                  // reuse after gemmA
    unsigned short* Kb   = (unsigned short*)(ws + 117440512);   // 4.2 MB
    unsigned short* Vt   = (unsigned short*)(ws + 121634816);   // 4.2 MB

    k_conv_bf16<<<8192, 256, 0, stream>>>(x, xb, 2097152);
    k_transpose_f32<<<dim3(96, 64), 256, 0, stream>>>(w_qkv, wT, 4096, 6144, 0);
    k_gemmA<<<256, 512, 0, stream>>>(xb, wT, qkvb, 6144, 4096);
    k_rope_pack<<<dim3(5, 2048), 128, 0, stream>>>(qkvb, cosT, sinT, Qb, Kb);
    k_transpose_b16<<<dim3(16, 32), 256, 0, stream>>>(qkvb, Vt, 2048, 6144, 5120);   // V^T
    k_transpose_f32<<<dim3(64, 64), 256, 0, stream>>>(w_o, wT, 4096, 4096, 0);
    k_attn<<<dim3(8, 32), 512, 0, stream>>>(Qb, Kb, Vt, Ob);
    k_gemmB<<<256, 512, 0, stream>>>(Ob, wT, out, 4096, 4096);
}

// Round 15
// 353.065 us; speedup vs baseline: 1.0074x; 1.0074x over previous
//
#include <hip/hip_runtime.h>
#include <stdint.h>

typedef float f32x4 __attribute__((ext_vector_type(4)));
typedef short s16x8 __attribute__((ext_vector_type(8)));
typedef unsigned short u16x4 __attribute__((ext_vector_type(4)));
typedef unsigned short u16x8 __attribute__((ext_vector_type(8)));

#define SCALE_F 0.08838834764831845f

__device__ __forceinline__ unsigned short f32_to_bf16(float f) {
    union { float f; unsigned int u; } v; v.f = f;
    return (unsigned short)((v.u + 0x7FFFu + ((v.u >> 16) & 1u)) >> 16);
}
__device__ __forceinline__ float bf16_to_f32(unsigned short h) {
    union { unsigned int u; float f; } v; v.u = (unsigned int)h << 16;
    return v.f;
}

__device__ __forceinline__ void gload16(const void* g, void* l) {
    __builtin_amdgcn_global_load_lds((const __attribute__((address_space(1))) unsigned int*)g,
                                     (__attribute__((address_space(3))) unsigned int*)l,
                                     16, 0, 0);
}

// ---------------- fp32 -> bf16 elementwise (8 elems/thread) ----------------
__global__ void k_conv_bf16(const float* __restrict__ in, unsigned short* __restrict__ out, int n8) {
    int i = blockIdx.x * 256 + threadIdx.x;
    if (i >= n8) return;
    f32x4 v0 = ((const f32x4*)in)[i * 2];
    f32x4 v1 = ((const f32x4*)in)[i * 2 + 1];
    u16x8 o;
    o[0] = f32_to_bf16(v0[0]); o[1] = f32_to_bf16(v0[1]);
    o[2] = f32_to_bf16(v0[2]); o[3] = f32_to_bf16(v0[3]);
    o[4] = f32_to_bf16(v1[0]); o[5] = f32_to_bf16(v1[1]);
    o[6] = f32_to_bf16(v1[2]); o[7] = f32_to_bf16(v1[3]);
    ((u16x8*)out)[i] = o;
}

// ------- fp32 [R][in_ld] (col offset in_off) -> bf16 [C][R] -------
__global__ void k_transpose_f32(const float* __restrict__ in, unsigned short* __restrict__ out,
                                int R, int in_ld, int in_off) {
    __shared__ float tile[64][65];
    const int rb = blockIdx.y * 64, cb = blockIdx.x * 64;
    const int t = threadIdx.x;
    const int lr = t >> 4, lc4 = (t & 15) * 4;
#pragma unroll
    for (int i = 0; i < 4; ++i) {
        int r = i * 16 + lr;
        f32x4 v = *(const f32x4*)(in + (size_t)(rb + r) * in_ld + in_off + cb + lc4);
        tile[r][lc4 + 0] = v[0]; tile[r][lc4 + 1] = v[1];
        tile[r][lc4 + 2] = v[2]; tile[r][lc4 + 3] = v[3];
    }
    __syncthreads();
#pragma unroll
    for (int i = 0; i < 4; ++i) {
        int oc = cb + i * 16 + lr;
        u16x4 o;
#pragma unroll
        for (int j = 0; j < 4; ++j)
            o[j] = f32_to_bf16(tile[lc4 + j][i * 16 + lr]);
        *(u16x4*)(out + (size_t)oc * R + rb + lc4) = o;
    }
}

// ------- bf16 [R][in_ld] (col offset in_off) -> bf16 [C][R] -------
__global__ void k_transpose_b16(const unsigned short* __restrict__ in, unsigned short* __restrict__ out,
                                int R, int in_ld, int in_off) {
    __shared__ unsigned short tile[64][68];
    const int rb = blockIdx.y * 64, cb = blockIdx.x * 64;
    const int t = threadIdx.x;
    const int lr = t >> 4, lc4 = (t & 15) * 4;
#pragma unroll
    for (int i = 0; i < 4; ++i) {
        int r = i * 16 + lr;
        u16x4 v = *(const u16x4*)(in + (size_t)(rb + r) * in_ld + in_off + cb + lc4);
        tile[r][lc4 + 0] = v[0]; tile[r][lc4 + 1] = v[1];
        tile[r][lc4 + 2] = v[2]; tile[r][lc4 + 3] = v[3];
    }
    __syncthreads();
#pragma unroll
    for (int i = 0; i < 4; ++i) {
        int oc = cb + i * 16 + lr;
        u16x4 o;
#pragma unroll
        for (int j = 0; j < 4; ++j)
            o[j] = tile[lc4 + j][i * 16 + lr];
        *(u16x4*)(out + (size_t)oc * R + rb + lc4) = o;
    }
}

// ======== gemmA: BM=128, BN=384, BK=64, full-fill grid 16x16=256, bn-major swizzle ========
__global__ __launch_bounds__(512, 1)
void k_gemmA(const unsigned short* __restrict__ A, const unsigned short* __restrict__ Bt,
             unsigned short* __restrict__ C, int N, int K) {
    __shared__ __align__(16) unsigned short As[2][2][4096];
    __shared__ __align__(16) unsigned short Bs[2][2][12288];
    const int tid = threadIdx.x;
    const int lane = tid & 63, wid = tid >> 6;
    const int g = lane >> 4, l15 = lane & 15;
    const int wm = wid >> 2, wn = wid & 3;
    const int nwg = gridDim.x, bid = blockIdx.x;
    const int swz = (bid & 7) * (nwg >> 3) + (bid >> 3);   // bijective: 256 % 8 == 0
    const int bn = swz >> 4, bm = swz & 15;                // bn-major XCD ownership
    const int brow = bm << 7, bcol = bn * 384;

    const int rS = tid >> 2;
    const int kcS = (tid & 3) ^ (rS & 3) ^ ((rS >> 2) & 3);
    const unsigned short* sA = A + (size_t)(brow + rS) * K + kcS * 8;
    const unsigned short* sB = Bt + (size_t)(bcol + rS) * K + kcS * 8;
    const int fsw = (g ^ (l15 & 3) ^ ((l15 >> 2) & 3)) * 8;

    f32x4 acc[4][6] = {};
    const int nt = K >> 6;

    auto stA = [&](int t, int kh) {
        gload16(sA + (size_t)t * 64 + kh * 32, &As[t & 1][kh][tid * 8]);
    };
    auto stB = [&](int t, int kh) {
        unsigned short* d = &Bs[t & 1][kh][tid * 8];
        const unsigned short* s = sB + (size_t)t * 64 + kh * 32;
        gload16(s, d);
        gload16(s + (size_t)128 * K, d + 4096);
        gload16(s + (size_t)256 * K, d + 8192);
    };

    stA(0, 0); stB(0, 0); stA(0, 1); stB(0, 1);

    for (int t = 0; t < nt; ++t) {
        const int c = t & 1;
#pragma unroll
        for (int kh = 0; kh < 2; ++kh) {
            if (t + 1 < nt)   { stA(t + 1, kh); stB(t + 1, kh); asm volatile("s_waitcnt vmcnt(8)" ::: "memory"); }
            else if (kh == 0) { asm volatile("s_waitcnt vmcnt(4)" ::: "memory"); }
            else              { asm volatile("s_waitcnt vmcnt(0)" ::: "memory"); }
            __builtin_amdgcn_s_barrier();
            s16x8 af[4], bf[6];
#pragma unroll
            for (int f = 0; f < 4; ++f)
                af[f] = *(const s16x8*)(&As[c][kh][(wm * 64 + f * 16 + l15) * 32 + fsw]);
#pragma unroll
            for (int j = 0; j < 6; ++j)
                bf[j] = *(const s16x8*)(&Bs[c][kh][(wn * 96 + j * 16 + l15) * 32 + fsw]);
            __builtin_amdgcn_s_setprio(1);
#pragma unroll
            for (int f = 0; f < 4; ++f)
#pragma unroll
                for (int j = 0; j < 6; ++j)
                    acc[f][j] = __builtin_amdgcn_mfma_f32_16x16x32_bf16(af[f], bf[j], acc[f][j], 0, 0, 0);
            __builtin_amdgcn_s_setprio(0);
        }
    }

#pragma unroll
    for (int f = 0; f < 4; ++f)
#pragma unroll
        for (int j = 0; j < 6; ++j)
#pragma unroll
            for (int r = 0; r < 4; ++r)
                C[(size_t)(brow + wm * 64 + f * 16 + g * 4 + r) * N
                  + bcol + wn * 96 + j * 16 + l15] = f32_to_bf16(acc[f][j][r]);
}

// ======== gemmB: BM=128, BN=256, BK=64, 2 phases/tile, bn-major swizzle ========
__global__ __launch_bounds__(512, 1)
void k_gemmB(const unsigned short* __restrict__ A, const unsigned short* __restrict__ Bt,
             float* __restrict__ C, int N, int K) {
    __shared__ __align__(16) unsigned short As[2][2][4096];
    __shared__ __align__(16) unsigned short Bs[2][2][8192];
    const int tid = threadIdx.x;
    const int lane = tid & 63, wid = tid >> 6;
    const int g = lane >> 4, l15 = lane & 15;
    const int wm = wid >> 2, wn = wid & 3;
    const int nwg = gridDim.x, bid = blockIdx.x;
    const int swz = (bid & 7) * (nwg >> 3) + (bid >> 3);
    const int bn = swz >> 4, bm = swz & 15;
    const int brow = bm << 7, bcol = bn << 8;

    const int rS = tid >> 2;
    const int kcS = (tid & 3) ^ (rS & 3) ^ ((rS >> 2) & 3);
    const unsigned short* sA = A + (size_t)(brow + rS) * K + kcS * 8;
    const unsigned short* sB = Bt + (size_t)(bcol + rS) * K + kcS * 8;
    const int fsw = (g ^ (l15 & 3) ^ ((l15 >> 2) & 3)) * 8;

    f32x4 acc[4][4] = {};
    const int nt = K >> 6;

    auto stA = [&](int t, int kh) {
        gload16(sA + (size_t)t * 64 + kh * 32, &As[t & 1][kh][tid * 8]);
    };
    auto stB = [&](int t, int kh) {
        unsigned short* d = &Bs[t & 1][kh][tid * 8];
        const unsigned short* s = sB + (size_t)t * 64 + kh * 32;
        gload16(s, d);
        gload16(s + (size_t)128 * K, d + 4096);
    };

    stA(0, 0); stB(0, 0); stA(0, 1); stB(0, 1);

    for (int t = 0; t < nt; ++t) {
        const int c = t & 1;
#pragma unroll
        for (int kh = 0; kh < 2; ++kh) {
            if (t + 1 < nt) { stA(t + 1, kh); stB(t + 1, kh); asm volatile("s_waitcnt vmcnt(6)" ::: "memory"); }
            else if (kh == 0) { asm volatile("s_waitcnt vmcnt(3)" ::: "memory"); }
            else              { asm volatile("s_waitcnt vmcnt(0)" ::: "memory"); }
            __builtin_amdgcn_s_barrier();
            s16x8 af[4], bf[4];
#pragma unroll
            for (int f = 0; f < 4; ++f)
                af[f] = *(const s16x8*)(&As[c][kh][(wm * 64 + f * 16 + l15) * 32 + fsw]);
#pragma unroll
            for (int j = 0; j < 4; ++j)
                bf[j] = *(const s16x8*)(&Bs[c][kh][(wn * 64 + j * 16 + l15) * 32 + fsw]);
            __builtin_amdgcn_s_setprio(1);
#pragma unroll
            for (int f = 0; f < 4; ++f)
#pragma unroll
                for (int j = 0; j < 4; ++j)
                    acc[f][j] = __builtin_amdgcn_mfma_f32_16x16x32_bf16(af[f], bf[j], acc[f][j], 0, 0, 0);
            __builtin_amdgcn_s_setprio(0);
        }
    }

#pragma unroll
    for (int f = 0; f < 4; ++f)
#pragma unroll
        for (int j = 0; j < 4; ++j)
#pragma unroll
            for (int r = 0; r < 4; ++r)
                C[(size_t)(brow + wm * 64 + f * 16 + g * 4 + r) * N
                  + bcol + wn * 64 + j * 16 + l15] = acc[f][j][r];
}

// ---------------- vectorized RoPE + pack Q/K; Q pre-scaled by 1/sqrt(D) ----------------
__global__ void k_rope_pack(const unsigned short* __restrict__ qkv, const float* __restrict__ cosT,
                            const float* __restrict__ sinT, unsigned short* __restrict__ Qb,
                            unsigned short* __restrict__ Kb) {
    const int oct = blockIdx.x * 128 + threadIdx.x;
    if (oct >= 640) return;
    const int col = oct * 8;
    const int t = blockIdx.y;
    const int d = col & 127;
    const bool isQ = (col < 4096);
    const float post = isQ ? SCALE_F : 1.0f;
    u16x8 v8 = *(const u16x8*)(qkv + (size_t)t * 6144 + col);
    u16x8 o8;
    if (d < 64) {
        u16x8 p8 = *(const u16x8*)(qkv + (size_t)t * 6144 + (col ^ 32));
        f32x4 c0 = *(const f32x4*)(cosT + t * 64 + d);
        f32x4 c1 = *(const f32x4*)(cosT + t * 64 + d + 4);
        f32x4 s0 = *(const f32x4*)(sinT + t * 64 + d);
        f32x4 s1 = *(const f32x4*)(sinT + t * 64 + d + 4);
        const float sgn = (d < 32) ? -1.f : 1.f;
#pragma unroll
        for (int j = 0; j < 8; ++j) {
            float cc = (j < 4) ? c0[j] : c1[j - 4];
            float ss = (j < 4) ? s0[j] : s1[j - 4];
            float o = (bf16_to_f32(v8[j]) * cc + sgn * bf16_to_f32(p8[j]) * ss) * post;
            o8[j] = f32_to_bf16(o);
        }
    } else {
#pragma unroll
        for (int j = 0; j < 8; ++j)
            o8[j] = f32_to_bf16(bf16_to_f32(v8[j]) * post);
    }
    if (isQ) {
        const int h = col >> 7;
        *(u16x8*)(Qb + ((size_t)h * 2048 + t) * 128 + d) = o8;
    } else {
        const int hk = (col - 4096) >> 7;
        *(u16x8*)(Kb + ((size_t)hk * 2048 + t) * 128 + d) = o8;
    }
}

// ------- causal GQA flash attention (r13 measured-best): paired q-tiles, fused K/V reads -------
__global__ __launch_bounds__(256, 2)
void k_attn(const unsigned short* __restrict__ Qb, const unsigned short* __restrict__ Kb,
            const unsigned short* __restrict__ Vt, unsigned short* __restrict__ Ob) {
    __shared__ __align__(16) unsigned short Ks[2][8192];
    __shared__ __align__(16) unsigned short Vs[2][8192];
    __shared__ __align__(16) unsigned short Pl[2][4][1024];
    const int h = blockIdx.y, hk = h >> 2;
    const int qbA = blockIdx.x, qbB = 31 - qbA;
    const int tid = threadIdx.x, lane = tid & 63, wid = tid >> 6;
    const int g = lane >> 4, l15 = lane & 15;
    const int qrA = qbA * 64 + wid * 16, qrB = qbB * 64 + wid * 16;
    const int swz = (l15 & 7) << 4;

    s16x8 aqA[4], aqB[4];
#pragma unroll
    for (int kc = 0; kc < 4; ++kc) {
        aqA[kc] = *(const s16x8*)(Qb + ((size_t)h * 2048 + qrA + l15) * 128 + kc * 32 + g * 8);
        aqB[kc] = *(const s16x8*)(Qb + ((size_t)h * 2048 + qrB + l15) * 128 + kc * 32 + g * 8);
    }

    const unsigned short* gK = Kb + ((size_t)hk * 2048 + (tid & 63)) * 128 + (tid >> 6) * 8;
    const unsigned short* gV = Vt + ((size_t)hk * 128 + (tid & 127)) * 2048 + (tid >> 7) * 8;

    auto stage = [&](int kb) {
        unsigned short* dK = Ks[kb & 1] + tid * 8;
        unsigned short* dV = Vs[kb & 1] + tid * 8;
        const unsigned short* sK = gK + (size_t)kb * 8192;
        const unsigned short* sV = gV + kb * 64;
#pragma unroll
        for (int i = 0; i < 4; ++i) gload16(sK + i * 32, dK + i * 2048);
#pragma unroll
        for (int i = 0; i < 4; ++i) gload16(sV + i * 16, dV + i * 2048);
    };

    f32x4 oaccA[8] = {}, oaccB[8] = {};
    float mA = -1e30f, lA = 0.f, mB = -1e30f, lB = 0.f;

    auto sm = [&](f32x4* s, f32x4* oacc, float& mr, float& lr, int qrow0, int kb, char* pw) {
        const int q = qrow0 + l15;
        if (kb * 64 + 63 > qrow0) {
#pragma unroll
            for (int kt = 0; kt < 4; ++kt)
#pragma unroll
                for (int r = 0; r < 4; ++r)
                    if (kb * 64 + kt * 16 + g * 4 + r > q) s[kt][r] = -3e38f;
        }
        float mx = -3e38f;
#pragma unroll
        for (int kt = 0; kt < 4; ++kt)
#pragma unroll
            for (int r = 0; r < 4; ++r) mx = fmaxf(mx, s[kt][r]);
        mx = fmaxf(mx, __shfl_xor(mx, 16));
        mx = fmaxf(mx, __shfl_xor(mx, 32));
        if (!__all(mx - mr <= 8.0f)) {        // T13 defer-max
            const float mnew = fmaxf(mr, mx);
            const float scal = __expf(mr - mnew);
            mr = mnew;
            float so[4];
#pragma unroll
            for (int r = 0; r < 4; ++r) so[r] = __shfl(scal, g * 4 + r, 16);
#pragma unroll
            for (int j = 0; j < 8; ++j) {
                oacc[j][0] *= so[0]; oacc[j][1] *= so[1];
                oacc[j][2] *= so[2]; oacc[j][3] *= so[3];
            }
            lr *= scal;
        }
        float ps = 0.f;
#pragma unroll
        for (int kt = 0; kt < 4; ++kt)
#pragma unroll
            for (int r = 0; r < 4; ++r) {
                float p = __expf(s[kt][r] - mr);
                s[kt][r] = p;
                ps += p;
            }
        ps += __shfl_xor(ps, 16);
        ps += __shfl_xor(ps, 32);
        lr += ps;
#pragma unroll
        for (int kt = 0; kt < 4; ++kt) {
            unsigned int w0 = (unsigned int)f32_to_bf16(s[kt][0]) | ((unsigned int)f32_to_bf16(s[kt][1]) << 16);
            unsigned int w1 = (unsigned int)f32_to_bf16(s[kt][2]) | ((unsigned int)f32_to_bf16(s[kt][3]) << 16);
            const int b0 = (l15 * 128 + kt * 32 + g * 8) ^ swz;
            *(unsigned int*)(pw + b0) = w0;
            *(unsigned int*)(pw + b0 + 4) = w1;
        }
    };

    const int nkb = qbB + 1;
    stage(0);
    for (int kb = 0; kb < nkb; ++kb) {
        if (kb + 1 < nkb) {
            stage(kb + 1);
            asm volatile("s_waitcnt vmcnt(8)" ::: "memory");
        } else {
            asm volatile("s_waitcnt vmcnt(0)" ::: "memory");
        }
        __builtin_amdgcn_s_barrier();
        const unsigned short* ks = Ks[kb & 1];
        const unsigned short* vs = Vs[kb & 1];
        char* pwA = (char*)Pl[0][wid];
        char* pwB = (char*)Pl[1][wid];
        const bool doA = (kb <= qbA);
        f32x4 sB_[4] = {}, sA_[4] = {};
        __builtin_amdgcn_s_setprio(1);
        if (doA) {
#pragma unroll
            for (int kc = 0; kc < 4; ++kc)
#pragma unroll
                for (int kt = 0; kt < 4; ++kt) {
                    s16x8 kf = *(const s16x8*)(ks + ((kc * 4 + g) * 64 + kt * 16 + l15) * 8);
                    sB_[kt] = __builtin_amdgcn_mfma_f32_16x16x32_bf16(kf, aqB[kc], sB_[kt], 0, 0, 0);
                    sA_[kt] = __builtin_amdgcn_mfma_f32_16x16x32_bf16(kf, aqA[kc], sA_[kt], 0, 0, 0);
                }
        } else {
#pragma unroll
            for (int kc = 0; kc < 4; ++kc)
#pragma unroll
                for (int kt = 0; kt < 4; ++kt) {
                    s16x8 kf = *(const s16x8*)(ks + ((kc * 4 + g) * 64 + kt * 16 + l15) * 8);
                    sB_[kt] = __builtin_amdgcn_mfma_f32_16x16x32_bf16(kf, aqB[kc], sB_[kt], 0, 0, 0);
                }
        }
        __builtin_amdgcn_s_setprio(0);
        sm(sB_, oaccB, mB, lB, qrB, kb, pwB);
        if (doA) sm(sA_, oaccA, mA, lA, qrA, kb, pwA);
        __builtin_amdgcn_s_setprio(1);
        if (doA) {
#pragma unroll
            for (int kc = 0; kc < 2; ++kc) {
                s16x8 paB = *(const s16x8*)(pwB + ((l15 * 128 + kc * 64 + g * 16) ^ swz));
                s16x8 paA = *(const s16x8*)(pwA + ((l15 * 128 + kc * 64 + g * 16) ^ swz));
#pragma unroll
                for (int j = 0; j < 8; ++j) {
                    s16x8 bv = *(const s16x8*)(vs + ((kc * 4 + g) * 128 + j * 16 + l15) * 8);
                    oaccB[j] = __builtin_amdgcn_mfma_f32_16x16x32_bf16(paB, bv, oaccB[j], 0, 0, 0);
                    oaccA[j] = __builtin_amdgcn_mfma_f32_16x16x32_bf16(paA, bv, oaccA[j], 0, 0, 0);
                }
            }
        } else {
#pragma unroll
            for (int kc = 0; kc < 2; ++kc) {
                s16x8 paB = *(const s16x8*)(pwB + ((l15 * 128 + kc * 64 + g * 16) ^ swz));
#pragma unroll
                for (int j = 0; j < 8; ++j) {
                    s16x8 bv = *(const s16x8*)(vs + ((kc * 4 + g) * 128 + j * 16 + l15) * 8);
                    oaccB[j] = __builtin_amdgcn_mfma_f32_16x16x32_bf16(paB, bv, oaccB[j], 0, 0, 0);
                }
            }
        }
        __builtin_amdgcn_s_setprio(0);
        __builtin_amdgcn_s_barrier();
    }
    float liA[4], liB[4];
#pragma unroll
    for (int r = 0; r < 4; ++r) {
        liA[r] = 1.f / __shfl(lA, g * 4 + r, 16);
        liB[r] = 1.f / __shfl(lB, g * 4 + r, 16);
    }
#pragma unroll
    for (int j = 0; j < 8; ++j)
#pragma unroll
        for (int r = 0; r < 4; ++r) {
            Ob[(size_t)(qrA + g * 4 + r) * 4096 + h * 128 + j * 16 + l15] = f32_to_bf16(oaccA[j][r] * liA[r]);
            Ob[(size_t)(qrB + g * 4 + r) * 4096 + h * 128 + j * 16 + l15] = f32_to_bf16(oaccB[j][r] * liB[r]);
        }
}

extern "C" void kernel_launch(void* const* d_in, const int* in_sizes, int n_in,
                              void* d_out, int out_size, void* d_ws, size_t ws_size,
                              hipStream_t stream) {
    const float* x     = (const float*)d_in[0];
    const float* cosT  = (const float*)d_in[2];
    const float* sinT  = (const float*)d_in[3];
    const float* w_qkv = (const float*)d_in[4];
    const float* w_o   = (const float*)d_in[5];
    float* out = (float*)d_out;

    char* ws = (char*)d_ws;
    unsigned short* wT   = (unsigned short*)(ws + 0);           // 50.3 MB (w_qkv^T / w_o^T)
    unsigned short* qkvb = (unsigned short*)(ws + 50331648);    // 25.2 MB bf16 qkv
    unsigned short* Ob   = (unsigned short*)(ws + 50331648);    // reuse after rope+t_V
    unsigned short* xb   = (unsigned short*)(ws + 100663296);   // 16.8 MB
    unsigned short* Qb   = xb;                                  // reuse after gemmA
    unsigned short* Kb   = (unsigned short*)(ws + 117440512);   // 4.2 MB
    unsigned short* Vt   = (unsigned short*)(ws + 121634816);   // 4.2 MB

    k_conv_bf16<<<4096, 256, 0, stream>>>(x, xb, 1048576);
    k_transpose_f32<<<dim3(96, 64), 256, 0, stream>>>(w_qkv, wT, 4096, 6144, 0);
    k_gemmA<<<256, 512, 0, stream>>>(xb, wT, qkvb, 6144, 4096);
    k_rope_pack<<<dim3(5, 2048), 128, 0, stream>>>(qkvb, cosT, sinT, Qb, Kb);
    k_transpose_b16<<<dim3(16, 32), 256, 0, stream>>>(qkvb, Vt, 2048, 6144, 5120);   // V^T
    k_transpose_f32<<<dim3(64, 64), 256, 0, stream>>>(w_o, wT, 4096, 4096, 0);
    k_attn<<<dim3(16, 32), 256, 0, stream>>>(Qb, Kb, Vt, Ob);
    k_gemmB<<<256, 512, 0, stream>>>(Ob, wT, out, 4096, 4096);
}

// Round 16
// 351.619 us; speedup vs baseline: 1.0115x; 1.0041x over previous
//
#include <hip/hip_runtime.h>
#include <stdint.h>

typedef float f32x4 __attribute__((ext_vector_type(4)));
typedef short s16x8 __attribute__((ext_vector_type(8)));
typedef unsigned short u16x4 __attribute__((ext_vector_type(4)));
typedef unsigned short u16x8 __attribute__((ext_vector_type(8)));

#define SCALE_F 0.08838834764831845f

__device__ __forceinline__ unsigned short f32_to_bf16(float f) {
    union { float f; unsigned int u; } v; v.f = f;
    return (unsigned short)((v.u + 0x7FFFu + ((v.u >> 16) & 1u)) >> 16);
}
__device__ __forceinline__ float bf16_to_f32(unsigned short h) {
    union { unsigned int u; float f; } v; v.u = (unsigned int)h << 16;
    return v.f;
}

__device__ __forceinline__ void gload16(const void* g, void* l) {
    __builtin_amdgcn_global_load_lds((const __attribute__((address_space(1))) unsigned int*)g,
                                     (__attribute__((address_space(3))) unsigned int*)l,
                                     16, 0, 0);
}

// ---------------- fp32 -> bf16 elementwise (8 elems/thread) ----------------
__global__ void k_conv_bf16(const float* __restrict__ in, unsigned short* __restrict__ out, int n8) {
    int i = blockIdx.x * 256 + threadIdx.x;
    if (i >= n8) return;
    f32x4 v0 = ((const f32x4*)in)[i * 2];
    f32x4 v1 = ((const f32x4*)in)[i * 2 + 1];
    u16x8 o;
    o[0] = f32_to_bf16(v0[0]); o[1] = f32_to_bf16(v0[1]);
    o[2] = f32_to_bf16(v0[2]); o[3] = f32_to_bf16(v0[3]);
    o[4] = f32_to_bf16(v1[0]); o[5] = f32_to_bf16(v1[1]);
    o[6] = f32_to_bf16(v1[2]); o[7] = f32_to_bf16(v1[3]);
    ((u16x8*)out)[i] = o;
}

// ------- fp32 [R][in_ld] (col offset in_off) -> bf16 [C][R] -------
__global__ void k_transpose_f32(const float* __restrict__ in, unsigned short* __restrict__ out,
                                int R, int in_ld, int in_off) {
    __shared__ float tile[64][65];
    const int rb = blockIdx.y * 64, cb = blockIdx.x * 64;
    const int t = threadIdx.x;
    const int lr = t >> 4, lc4 = (t & 15) * 4;
#pragma unroll
    for (int i = 0; i < 4; ++i) {
        int r = i * 16 + lr;
        f32x4 v = *(const f32x4*)(in + (size_t)(rb + r) * in_ld + in_off + cb + lc4);
        tile[r][lc4 + 0] = v[0]; tile[r][lc4 + 1] = v[1];
        tile[r][lc4 + 2] = v[2]; tile[r][lc4 + 3] = v[3];
    }
    __syncthreads();
#pragma unroll
    for (int i = 0; i < 4; ++i) {
        int oc = cb + i * 16 + lr;
        u16x4 o;
#pragma unroll
        for (int j = 0; j < 4; ++j)
            o[j] = f32_to_bf16(tile[lc4 + j][i * 16 + lr]);
        *(u16x4*)(out + (size_t)oc * R + rb + lc4) = o;
    }
}

// ------- bf16 [R][in_ld] (col offset in_off) -> bf16 [C][R] -------
__global__ void k_transpose_b16(const unsigned short* __restrict__ in, unsigned short* __restrict__ out,
                                int R, int in_ld, int in_off) {
    __shared__ unsigned short tile[64][68];
    const int rb = blockIdx.y * 64, cb = blockIdx.x * 64;
    const int t = threadIdx.x;
    const int lr = t >> 4, lc4 = (t & 15) * 4;
#pragma unroll
    for (int i = 0; i < 4; ++i) {
        int r = i * 16 + lr;
        u16x4 v = *(const u16x4*)(in + (size_t)(rb + r) * in_ld + in_off + cb + lc4);
        tile[r][lc4 + 0] = v[0]; tile[r][lc4 + 1] = v[1];
        tile[r][lc4 + 2] = v[2]; tile[r][lc4 + 3] = v[3];
    }
    __syncthreads();
#pragma unroll
    for (int i = 0; i < 4; ++i) {
        int oc = cb + i * 16 + lr;
        u16x4 o;
#pragma unroll
        for (int j = 0; j < 4; ++j)
            o[j] = tile[lc4 + j][i * 16 + lr];
        *(u16x4*)(out + (size_t)oc * R + rb + lc4) = o;
    }
}

// ======== gemmA: BM=128, BN=384, BK=64, full-fill grid 16x16=256, bn-major swizzle ========
__global__ __launch_bounds__(512, 1)
void k_gemmA(const unsigned short* __restrict__ A, const unsigned short* __restrict__ Bt,
             unsigned short* __restrict__ C, int N, int K) {
    __shared__ __align__(16) unsigned short As[2][2][4096];
    __shared__ __align__(16) unsigned short Bs[2][2][12288];
    const int tid = threadIdx.x;
    const int lane = tid & 63, wid = tid >> 6;
    const int g = lane >> 4, l15 = lane & 15;
    const int wm = wid >> 2, wn = wid & 3;
    const int nwg = gridDim.x, bid = blockIdx.x;
    const int swz = (bid & 7) * (nwg >> 3) + (bid >> 3);   // bijective: 256 % 8 == 0
    const int bn = swz >> 4, bm = swz & 15;                // bn-major XCD ownership
    const int brow = bm << 7, bcol = bn * 384;

    const int rS = tid >> 2;
    const int kcS = (tid & 3) ^ (rS & 3) ^ ((rS >> 2) & 3);
    const unsigned short* sA = A + (size_t)(brow + rS) * K + kcS * 8;
    const unsigned short* sB = Bt + (size_t)(bcol + rS) * K + kcS * 8;
    const int fsw = (g ^ (l15 & 3) ^ ((l15 >> 2) & 3)) * 8;

    f32x4 acc[4][6] = {};
    const int nt = K >> 6;

    auto stA = [&](int t, int kh) {
        gload16(sA + (size_t)t * 64 + kh * 32, &As[t & 1][kh][tid * 8]);
    };
    auto stB = [&](int t, int kh) {
        unsigned short* d = &Bs[t & 1][kh][tid * 8];
        const unsigned short* s = sB + (size_t)t * 64 + kh * 32;
        gload16(s, d);
        gload16(s + (size_t)128 * K, d + 4096);
        gload16(s + (size_t)256 * K, d + 8192);
    };

    stA(0, 0); stB(0, 0); stA(0, 1); stB(0, 1);

    for (int t = 0; t < nt; ++t) {
        const int c = t & 1;
#pragma unroll
        for (int kh = 0; kh < 2; ++kh) {
            if (t + 1 < nt)   { stA(t + 1, kh); stB(t + 1, kh); asm volatile("s_waitcnt vmcnt(8)" ::: "memory"); }
            else if (kh == 0) { asm volatile("s_waitcnt vmcnt(4)" ::: "memory"); }
            else              { asm volatile("s_waitcnt vmcnt(0)" ::: "memory"); }
            __builtin_amdgcn_s_barrier();
            s16x8 af[4], bf[6];
#pragma unroll
            for (int f = 0; f < 4; ++f)
                af[f] = *(const s16x8*)(&As[c][kh][(wm * 64 + f * 16 + l15) * 32 + fsw]);
#pragma unroll
            for (int j = 0; j < 6; ++j)
                bf[j] = *(const s16x8*)(&Bs[c][kh][(wn * 96 + j * 16 + l15) * 32 + fsw]);
            __builtin_amdgcn_s_setprio(1);
#pragma unroll
            for (int f = 0; f < 4; ++f)
#pragma unroll
                for (int j = 0; j < 6; ++j)
                    acc[f][j] = __builtin_amdgcn_mfma_f32_16x16x32_bf16(af[f], bf[j], acc[f][j], 0, 0, 0);
            __builtin_amdgcn_s_setprio(0);
        }
    }

#pragma unroll
    for (int f = 0; f < 4; ++f)
#pragma unroll
        for (int j = 0; j < 6; ++j)
#pragma unroll
            for (int r = 0; r < 4; ++r)
                C[(size_t)(brow + wm * 64 + f * 16 + g * 4 + r) * N
                  + bcol + wn * 96 + j * 16 + l15] = f32_to_bf16(acc[f][j][r]);
}

// ======== gemmB: BM=128, BN=256, BK=64, 2 phases/tile, bn-major swizzle ========
__global__ __launch_bounds__(512, 1)
void k_gemmB(const unsigned short* __restrict__ A, const unsigned short* __restrict__ Bt,
             float* __restrict__ C, int N, int K) {
    __shared__ __align__(16) unsigned short As[2][2][4096];
    __shared__ __align__(16) unsigned short Bs[2][2][8192];
    const int tid = threadIdx.x;
    const int lane = tid & 63, wid = tid >> 6;
    const int g = lane >> 4, l15 = lane & 15;
    const int wm = wid >> 2, wn = wid & 3;
    const int nwg = gridDim.x, bid = blockIdx.x;
    const int swz = (bid & 7) * (nwg >> 3) + (bid >> 3);
    const int bn = swz >> 4, bm = swz & 15;
    const int brow = bm << 7, bcol = bn << 8;

    const int rS = tid >> 2;
    const int kcS = (tid & 3) ^ (rS & 3) ^ ((rS >> 2) & 3);
    const unsigned short* sA = A + (size_t)(brow + rS) * K + kcS * 8;
    const unsigned short* sB = Bt + (size_t)(bcol + rS) * K + kcS * 8;
    const int fsw = (g ^ (l15 & 3) ^ ((l15 >> 2) & 3)) * 8;

    f32x4 acc[4][4] = {};
    const int nt = K >> 6;

    auto stA = [&](int t, int kh) {
        gload16(sA + (size_t)t * 64 + kh * 32, &As[t & 1][kh][tid * 8]);
    };
    auto stB = [&](int t, int kh) {
        unsigned short* d = &Bs[t & 1][kh][tid * 8];
        const unsigned short* s = sB + (size_t)t * 64 + kh * 32;
        gload16(s, d);
        gload16(s + (size_t)128 * K, d + 4096);
    };

    stA(0, 0); stB(0, 0); stA(0, 1); stB(0, 1);

    for (int t = 0; t < nt; ++t) {
        const int c = t & 1;
#pragma unroll
        for (int kh = 0; kh < 2; ++kh) {
            if (t + 1 < nt) { stA(t + 1, kh); stB(t + 1, kh); asm volatile("s_waitcnt vmcnt(6)" ::: "memory"); }
            else if (kh == 0) { asm volatile("s_waitcnt vmcnt(3)" ::: "memory"); }
            else              { asm volatile("s_waitcnt vmcnt(0)" ::: "memory"); }
            __builtin_amdgcn_s_barrier();
            s16x8 af[4], bf[4];
#pragma unroll
            for (int f = 0; f < 4; ++f)
                af[f] = *(const s16x8*)(&As[c][kh][(wm * 64 + f * 16 + l15) * 32 + fsw]);
#pragma unroll
            for (int j = 0; j < 4; ++j)
                bf[j] = *(const s16x8*)(&Bs[c][kh][(wn * 64 + j * 16 + l15) * 32 + fsw]);
            __builtin_amdgcn_s_setprio(1);
#pragma unroll
            for (int f = 0; f < 4; ++f)
#pragma unroll
                for (int j = 0; j < 4; ++j)
                    acc[f][j] = __builtin_amdgcn_mfma_f32_16x16x32_bf16(af[f], bf[j], acc[f][j], 0, 0, 0);
            __builtin_amdgcn_s_setprio(0);
        }
    }

#pragma unroll
    for (int f = 0; f < 4; ++f)
#pragma unroll
        for (int j = 0; j < 4; ++j)
#pragma unroll
            for (int r = 0; r < 4; ++r)
                C[(size_t)(brow + wm * 64 + f * 16 + g * 4 + r) * N
                  + bcol + wn * 64 + j * 16 + l15] = acc[f][j][r];
}

// ---------------- vectorized RoPE + pack Q/K; Q pre-scaled by 1/sqrt(D) ----------------
__global__ void k_rope_pack(const unsigned short* __restrict__ qkv, const float* __restrict__ cosT,
                            const float* __restrict__ sinT, unsigned short* __restrict__ Qb,
                            unsigned short* __restrict__ Kb) {
    const int oct = blockIdx.x * 128 + threadIdx.x;
    if (oct >= 640) return;
    const int col = oct * 8;
    const int t = blockIdx.y;
    const int d = col & 127;
    const bool isQ = (col < 4096);
    const float post = isQ ? SCALE_F : 1.0f;
    u16x8 v8 = *(const u16x8*)(qkv + (size_t)t * 6144 + col);
    u16x8 o8;
    if (d < 64) {
        u16x8 p8 = *(const u16x8*)(qkv + (size_t)t * 6144 + (col ^ 32));
        f32x4 c0 = *(const f32x4*)(cosT + t * 64 + d);
        f32x4 c1 = *(const f32x4*)(cosT + t * 64 + d + 4);
        f32x4 s0 = *(const f32x4*)(sinT + t * 64 + d);
        f32x4 s1 = *(const f32x4*)(sinT + t * 64 + d + 4);
        const float sgn = (d < 32) ? -1.f : 1.f;
#pragma unroll
        for (int j = 0; j < 8; ++j) {
            float cc = (j < 4) ? c0[j] : c1[j - 4];
            float ss = (j < 4) ? s0[j] : s1[j - 4];
            float o = (bf16_to_f32(v8[j]) * cc + sgn * bf16_to_f32(p8[j]) * ss) * post;
            o8[j] = f32_to_bf16(o);
        }
    } else {
#pragma unroll
        for (int j = 0; j < 8; ++j)
            o8[j] = f32_to_bf16(bf16_to_f32(v8[j]) * post);
    }
    if (isQ) {
        const int h = col >> 7;
        *(u16x8*)(Qb + ((size_t)h * 2048 + t) * 128 + d) = o8;
    } else {
        const int hk = (col - 4096) >> 7;
        *(u16x8*)(Kb + ((size_t)hk * 2048 + t) * 128 + d) = o8;
    }
}

// ------- causal GQA flash attention (r13 measured-best): paired q-tiles, fused K/V reads -------
__global__ __launch_bounds__(256, 2)
void k_attn(const unsigned short* __restrict__ Qb, const unsigned short* __restrict__ Kb,
            const unsigned short* __restrict__ Vt, unsigned short* __restrict__ Ob) {
    __shared__ __align__(16) unsigned short Ks[2][8192];
    __shared__ __align__(16) unsigned short Vs[2][8192];
    __shared__ __align__(16) unsigned short Pl[2][4][1024];
    const int h = blockIdx.y, hk = h >> 2;
    const int qbA = blockIdx.x, qbB = 31 - qbA;
    const int tid = threadIdx.x, lane = tid & 63, wid = tid >> 6;
    const int g = lane >> 4, l15 = lane & 15;
    const int qrA = qbA * 64 + wid * 16, qrB = qbB * 64 + wid * 16;
    const int swz = (l15 & 7) << 4;

    s16x8 aqA[4], aqB[4];
#pragma unroll
    for (int kc = 0; kc < 4; ++kc) {
        aqA[kc] = *(const s16x8*)(Qb + ((size_t)h * 2048 + qrA + l15) * 128 + kc * 32 + g * 8);
        aqB[kc] = *(const s16x8*)(Qb + ((size_t)h * 2048 + qrB + l15) * 128 + kc * 32 + g * 8);
    }

    const unsigned short* gK = Kb + ((size_t)hk * 2048 + (tid & 63)) * 128 + (tid >> 6) * 8;
    const unsigned short* gV = Vt + ((size_t)hk * 128 + (tid & 127)) * 2048 + (tid >> 7) * 8;

    auto stage = [&](int kb) {
        unsigned short* dK = Ks[kb & 1] + tid * 8;
        unsigned short* dV = Vs[kb & 1] + tid * 8;
        const unsigned short* sK = gK + (size_t)kb * 8192;
        const unsigned short* sV = gV + kb * 64;
#pragma unroll
        for (int i = 0; i < 4; ++i) gload16(sK + i * 32, dK + i * 2048);
#pragma unroll
        for (int i = 0; i < 4; ++i) gload16(sV + i * 16, dV + i * 2048);
    };

    f32x4 oaccA[8] = {}, oaccB[8] = {};
    float mA = -1e30f, lA = 0.f, mB = -1e30f, lB = 0.f;

    auto sm = [&](f32x4* s, f32x4* oacc, float& mr, float& lr, int qrow0, int kb, char* pw) {
        const int q = qrow0 + l15;
        if (kb * 64 + 63 > qrow0) {
#pragma unroll
            for (int kt = 0; kt < 4; ++kt)
#pragma unroll
                for (int r = 0; r < 4; ++r)
                    if (kb * 64 + kt * 16 + g * 4 + r > q) s[kt][r] = -3e38f;
        }
        float mx = -3e38f;
#pragma unroll
        for (int kt = 0; kt < 4; ++kt)
#pragma unroll
            for (int r = 0; r < 4; ++r) mx = fmaxf(mx, s[kt][r]);
        mx = fmaxf(mx, __shfl_xor(mx, 16));
        mx = fmaxf(mx, __shfl_xor(mx, 32));
        if (!__all(mx - mr <= 8.0f)) {        // T13 defer-max
            const float mnew = fmaxf(mr, mx);
            const float scal = __expf(mr - mnew);
            mr = mnew;
            float so[4];
#pragma unroll
            for (int r = 0; r < 4; ++r) so[r] = __shfl(scal, g * 4 + r, 16);
#pragma unroll
            for (int j = 0; j < 8; ++j) {
                oacc[j][0] *= so[0]; oacc[j][1] *= so[1];
                oacc[j][2] *= so[2]; oacc[j][3] *= so[3];
            }
            lr *= scal;
        }
        float ps = 0.f;
#pragma unroll
        for (int kt = 0; kt < 4; ++kt)
#pragma unroll
            for (int r = 0; r < 4; ++r) {
                float p = __expf(s[kt][r] - mr);
                s[kt][r] = p;
                ps += p;
            }
        ps += __shfl_xor(ps, 16);
        ps += __shfl_xor(ps, 32);
        lr += ps;
#pragma unroll
        for (int kt = 0; kt < 4; ++kt) {
            unsigned int w0 = (unsigned int)f32_to_bf16(s[kt][0]) | ((unsigned int)f32_to_bf16(s[kt][1]) << 16);
            unsigned int w1 = (unsigned int)f32_to_bf16(s[kt][2]) | ((unsigned int)f32_to_bf16(s[kt][3]) << 16);
            const int b0 = (l15 * 128 + kt * 32 + g * 8) ^ swz;
            *(unsigned int*)(pw + b0) = w0;
            *(unsigned int*)(pw + b0 + 4) = w1;
        }
    };

    const int nkb = qbB + 1;
    stage(0);
    for (int kb = 0; kb < nkb; ++kb) {
        if (kb + 1 < nkb) {
            stage(kb + 1);
            asm volatile("s_waitcnt vmcnt(8)" ::: "memory");
        } else {
            asm volatile("s_waitcnt vmcnt(0)" ::: "memory");
        }
        __builtin_amdgcn_s_barrier();
        const unsigned short* ks = Ks[kb & 1];
        const unsigned short* vs = Vs[kb & 1];
        char* pwA = (char*)Pl[0][wid];
        char* pwB = (char*)Pl[1][wid];
        const bool doA = (kb <= qbA);
        f32x4 sB_[4] = {}, sA_[4] = {};
        __builtin_amdgcn_s_setprio(1);
        if (doA) {
#pragma unroll
            for (int kc = 0; kc < 4; ++kc)
#pragma unroll
                for (int kt = 0; kt < 4; ++kt) {
                    s16x8 kf = *(const s16x8*)(ks + ((kc * 4 + g) * 64 + kt * 16 + l15) * 8);
                    sB_[kt] = __builtin_amdgcn_mfma_f32_16x16x32_bf16(kf, aqB[kc], sB_[kt], 0, 0, 0);
                    sA_[kt] = __builtin_amdgcn_mfma_f32_16x16x32_bf16(kf, aqA[kc], sA_[kt], 0, 0, 0);
                }
        } else {
#pragma unroll
            for (int kc = 0; kc < 4; ++kc)
#pragma unroll
                for (int kt = 0; kt < 4; ++kt) {
                    s16x8 kf = *(const s16x8*)(ks + ((kc * 4 + g) * 64 + kt * 16 + l15) * 8);
                    sB_[kt] = __builtin_amdgcn_mfma_f32_16x16x32_bf16(kf, aqB[kc], sB_[kt], 0, 0, 0);
                }
        }
        __builtin_amdgcn_s_setprio(0);
        sm(sB_, oaccB, mB, lB, qrB, kb, pwB);
        if (doA) sm(sA_, oaccA, mA, lA, qrA, kb, pwA);
        __builtin_amdgcn_s_setprio(1);
        if (doA) {
#pragma unroll
            for (int kc = 0; kc < 2; ++kc) {
                s16x8 paB = *(const s16x8*)(pwB + ((l15 * 128 + kc * 64 + g * 16) ^ swz));
                s16x8 paA = *(const s16x8*)(pwA + ((l15 * 128 + kc * 64 + g * 16) ^ swz));
#pragma unroll
                for (int j = 0; j < 8; ++j) {
                    s16x8 bv = *(const s16x8*)(vs + ((kc * 4 + g) * 128 + j * 16 + l15) * 8);
                    oaccB[j] = __builtin_amdgcn_mfma_f32_16x16x32_bf16(paB, bv, oaccB[j], 0, 0, 0);
                    oaccA[j] = __builtin_amdgcn_mfma_f32_16x16x32_bf16(paA, bv, oaccA[j], 0, 0, 0);
                }
            }
        } else {
#pragma unroll
            for (int kc = 0; kc < 2; ++kc) {
                s16x8 paB = *(const s16x8*)(pwB + ((l15 * 128 + kc * 64 + g * 16) ^ swz));
#pragma unroll
                for (int j = 0; j < 8; ++j) {
                    s16x8 bv = *(const s16x8*)(vs + ((kc * 4 + g) * 128 + j * 16 + l15) * 8);
                    oaccB[j] = __builtin_amdgcn_mfma_f32_16x16x32_bf16(paB, bv, oaccB[j], 0, 0, 0);
                }
            }
        }
        __builtin_amdgcn_s_setprio(0);
        __builtin_amdgcn_s_barrier();
    }
    float liA[4], liB[4];
#pragma unroll
    for (int r = 0; r < 4; ++r) {
        liA[r] = 1.f / __shfl(lA, g * 4 + r, 16);
        liB[r] = 1.f / __shfl(lB, g * 4 + r, 16);
    }
#pragma unroll
    for (int j = 0; j < 8; ++j)
#pragma unroll
        for (int r = 0; r < 4; ++r) {
            Ob[(size_t)(qrA + g * 4 + r) * 4096 + h * 128 + j * 16 + l15] = f32_to_bf16(oaccA[j][r] * liA[r]);
            Ob[(size_t)(qrB + g * 4 + r) * 4096 + h * 128 + j * 16 + l15] = f32_to_bf16(oaccB[j][r] * liB[r]);
        }
}

extern "C" void kernel_launch(void* const* d_in, const int* in_sizes, int n_in,
                              void* d_out, int out_size, void* d_ws, size_t ws_size,
                              hipStream_t stream) {
    const float* x     = (const float*)d_in[0];
    const float* cosT  = (const float*)d_in[2];
    const float* sinT  = (const float*)d_in[3];
    const float* w_qkv = (const float*)d_in[4];
    const float* w_o   = (const float*)d_in[5];
    float* out = (float*)d_out;

    char* ws = (char*)d_ws;
    unsigned short* wT   = (unsigned short*)(ws + 0);           // 50.3 MB (w_qkv^T / w_o^T)
    unsigned short* qkvb = (unsigned short*)(ws + 50331648);    // 25.2 MB bf16 qkv
    unsigned short* Ob   = (unsigned short*)(ws + 50331648);    // reuse after rope+t_V
    unsigned short* xb   = (unsigned short*)(ws + 100663296);   // 16.8 MB
    unsigned short* Qb   = xb;                                  // reuse after gemmA
    unsigned short* Kb   = (unsigned short*)(ws + 117440512);   // 4.2 MB
    unsigned short* Vt   = (unsigned short*)(ws + 121634816);   // 4.2 MB

    k_conv_bf16<<<4096, 256, 0, stream>>>(x, xb, 1048576);
    k_transpose_f32<<<dim3(96, 64), 256, 0, stream>>>(w_qkv, wT, 4096, 6144, 0);
    k_gemmA<<<256, 512, 0, stream>>>(xb, wT, qkvb, 6144, 4096);
    k_rope_pack<<<dim3(5, 2048), 128, 0, stream>>>(qkvb, cosT, sinT, Qb, Kb);
    k_transpose_b16<<<dim3(16, 32), 256, 0, stream>>>(qkvb, Vt, 2048, 6144, 5120);   // V^T
    k_transpose_f32<<<dim3(64, 64), 256, 0, stream>>>(w_o, wT, 4096, 4096, 0);
    k_attn<<<dim3(16, 32), 256, 0, stream>>>(Qb, Kb, Vt, Ob);
    k_gemmB<<<256, 512, 0, stream>>>(Ob, wT, out, 4096, 4096);
}